// Round 5
// baseline (451.175 us; speedup 1.0000x reference)
//
#include <hip/hip_runtime.h>
#include <hip/hip_fp16.h>

// ---------------- problem constants ----------------
#define NNODES 100000

// ---------------- workspace layout (bytes) ----------------
#define OFF_W1TH     0UL            // ushort[128*256] = 65536
#define OFF_W1TL     65536UL        // ushort[128*256]
#define OFF_W2TH     131072UL       // ushort[64*128] = 16384
#define OFF_W2TL     147456UL       // ushort[64*128]  -> ends 163840
#define OFF_BCNT     163840UL       // int[512]
#define OFF_BBASE    165888UL       // int[512]
#define OFF_BCUR     167936UL       // int[512] -> ends 169984
#define OFF_ROWPTR   400128UL       // int[100001]
#define OFF_DINV     1200640UL      // float[100000]
#define OFF_COL      1605632UL      // int[1600000]  -> ends 8005632
#define OFF_EBUF     8005632UL      // int2[1600000] = 12.8MB (overlaps h1g; dead before gemm1)
#define OFF_H1G      8005632UL      // half[100000*128] = 25.6MB -> ends 33605632
#define OFF_H1OUT    59205632UL     // float[100000*128] -> ends 110405632
// h2g (half[100000*64]) reuses OFF_H1G (h1g dead after agg1)

typedef __attribute__((ext_vector_type(8))) short bf16x8;
typedef __attribute__((ext_vector_type(4))) float f32x4;

__device__ inline ushort f2bf(float f) {
    unsigned u = __float_as_uint(f);
    unsigned r = u + 0x7fffu + ((u >> 16) & 1u);  // round-to-nearest-even
    return (ushort)(r >> 16);
}
__device__ inline float bf2f(ushort h) { return __uint_as_float(((unsigned)h) << 16); }

// pack truncated-bf16 of two floats into one uint (lo=a, hi=b)
__device__ inline unsigned pack_hi(float a, float b) {
    return (__float_as_uint(a) >> 16) | (__float_as_uint(b) & 0xFFFF0000u);
}
// float value of truncated bf16 of a
__device__ inline float zlow(float a) {
    return __uint_as_float(__float_as_uint(a) & 0xFFFF0000u);
}

// =========== CSR build via 2-level counting sort (bucket = dst>>8) ===========
__global__ __launch_bounds__(256) void bincount(const int* __restrict__ dst,
                                                int* __restrict__ bcnt, int E) {
    __shared__ int lc[512];
    int t = threadIdx.x;
    lc[t] = 0; lc[t + 256] = 0;
    __syncthreads();
    for (int e = blockIdx.x * 256 + t; e < E; e += gridDim.x * 256)
        atomicAdd(&lc[dst[e] >> 8], 1);
    __syncthreads();
    if (lc[t]) atomicAdd(&bcnt[t], lc[t]);
    if (lc[t + 256]) atomicAdd(&bcnt[t + 256], lc[t + 256]);
}

__global__ __launch_bounds__(512) void bscan(const int* __restrict__ bcnt,
                                             int* __restrict__ bbase,
                                             int* __restrict__ bcur,
                                             int* __restrict__ rowptr,
                                             int NB, int N, int E) {
    __shared__ int s[512];
    int t = threadIdx.x;
    int v = (t < NB) ? bcnt[t] : 0;
    s[t] = v;
    __syncthreads();
    for (int off = 1; off < 512; off <<= 1) {
        int add = (t >= off) ? s[t - off] : 0;
        __syncthreads();
        s[t] += add;
        __syncthreads();
    }
    if (t < NB) {
        int ex = s[t] - v;
        bbase[t] = ex;
        bcur[t] = ex;
    }
    if (t == 0) rowptr[N] = E;
}

#define CHUNK 4096
__global__ __launch_bounds__(256) void binscatter(const int* __restrict__ src,
                                                  const int* __restrict__ dst,
                                                  int* __restrict__ bcur,
                                                  int2* __restrict__ ebuf, int E) {
    __shared__ int lc[512];
    __shared__ int gb[512];
    int t = threadIdx.x;
    lc[t] = 0; lc[t + 256] = 0;
    __syncthreads();
    int base = blockIdx.x * CHUNK;
    int rb[16];
#pragma unroll
    for (int i = 0; i < 16; ++i) {
        int e = base + i * 256 + t;
        if (e < E) {
            int b = dst[e] >> 8;
            rb[i] = (b << 12) | atomicAdd(&lc[b], 1);
        } else rb[i] = -1;
    }
    __syncthreads();
    if (lc[t]) gb[t] = atomicAdd(&bcur[t], lc[t]);
    if (lc[t + 256]) gb[t + 256] = atomicAdd(&bcur[t + 256], lc[t + 256]);
    __syncthreads();
#pragma unroll
    for (int i = 0; i < 16; ++i) {
        if (rb[i] >= 0) {
            int e = base + i * 256 + t;
            int b = rb[i] >> 12, r = rb[i] & 4095;
            ebuf[gb[b] + r] = make_int2(src[e], dst[e]);
        }
    }
}

__global__ __launch_bounds__(256) void buildcsr(const int2* __restrict__ ebuf,
                                                const int* __restrict__ bbase,
                                                const int* __restrict__ bcnt,
                                                int* __restrict__ rowptr,
                                                int* __restrict__ colarr,
                                                float* __restrict__ dinv, int N) {
    int b = blockIdx.x;
    int t = threadIdx.x;
    int start = bbase[b];
    int cnt = bcnt[b];
    int n0 = b << 8;
    __shared__ int nc[256];
    __shared__ int s[256];
    __shared__ int ncur[256];
    nc[t] = 0;
    __syncthreads();
    for (int e = t; e < cnt; e += 256) atomicAdd(&nc[ebuf[start + e].y - n0], 1);
    __syncthreads();
    int own = nc[t];
    s[t] = own;
    __syncthreads();
    for (int off = 1; off < 256; off <<= 1) {
        int add = (t >= off) ? s[t - off] : 0;
        __syncthreads();
        s[t] += add;
        __syncthreads();
    }
    int rowbase = start + s[t] - own;
    if (n0 + t < N) {
        rowptr[n0 + t] = rowbase;
        dinv[n0 + t] = rsqrtf((float)(own + 1));
    }
    ncur[t] = rowbase;
    __syncthreads();
    for (int e = t; e < cnt; e += 256) {
        int2 p = ebuf[start + e];
        int slot = atomicAdd(&ncur[p.y - n0], 1);
        colarr[slot] = p.x;
    }
}

// ---------------- split W [K][N] fp32 -> transposed bf16 hi/lo [N][K] ----------------
__global__ __launch_bounds__(256) void split_wt(const float* __restrict__ W,
                                                ushort* __restrict__ hi,
                                                ushort* __restrict__ lo,
                                                int K, int N) {
    int idx = blockIdx.x * 256 + threadIdx.x;
    if (idx >= K * N) return;
    int k = idx / N, n = idx - k * N;
    float v = W[idx];
    ushort h = f2bf(v);
    float rest = v - bf2f(h);
    hi[(size_t)n * K + k] = h;
    lo[(size_t)n * K + k] = f2bf(rest);
}

// ---------------- split-bf16 MFMA GEMM, KC=32, register-prefetch pipeline ----------------
// block tile 128(M) x BN, 4 waves (wave tile 32 x BN); LDS 40.96KB (BN=128) -> 3 blocks/CU
template <int BN, int KTOT>
__global__ __launch_bounds__(256, 3) void gemm_mfma(const float* __restrict__ A,
                                                    const ushort* __restrict__ Bh_g,
                                                    const ushort* __restrict__ Bl_g,
                                                    const float* __restrict__ dinv,
                                                    _Float16* __restrict__ C, int M) {
    constexpr int KC = 32;
    constexpr int LDK = KC + 8;  // 80B rows: 16B-aligned, 2-way bank alias (free)
    __shared__ ushort Ah[128][LDK];
    __shared__ ushort Al[128][LDK];
    __shared__ ushort Bh[BN][LDK];
    __shared__ ushort Bl[BN][LDK];

    const int tid = threadIdx.x;
    const int wave = tid >> 6;
    const int lane = tid & 63;
    const int lm = lane & 15;
    const int q = lane >> 4;
    const int m0 = blockIdx.x * 128;

    constexpr int NT = BN / 16;
    constexpr int BV = BN * KC / 8 / 256;  // uint4 per thread per B array (128->2, 64->1)

    f32x4 acc[2][NT];
#pragma unroll
    for (int a = 0; a < 2; ++a)
#pragma unroll
        for (int b = 0; b < NT; ++b) acc[a][b] = (f32x4){0.f, 0.f, 0.f, 0.f};

    // A staging slots: 128x32 floats = 1024 float4; per thread 4.  row=v>>3, kk=(v&7)*4
    // B staging slots: BN*32 ushorts = BN*4 uint4;   per thread BV. row=v>>2, kk=(v&3)*8
    float4 areg[4];
    uint4 bhreg[BV], blreg[BV];

    auto load_chunk = [&](int k0) {
#pragma unroll
        for (int i = 0; i < 4; ++i) {
            int v = tid + i * 256;
            int row = v >> 3;
            int kk = (v & 7) << 2;
            int gr = m0 + row;
            areg[i] = make_float4(0.f, 0.f, 0.f, 0.f);
            if (gr < M) areg[i] = *(const float4*)&A[(size_t)gr * KTOT + k0 + kk];
        }
#pragma unroll
        for (int i = 0; i < BV; ++i) {
            int v = tid + i * 256;
            int row = v >> 2;
            int kk = (v & 3) << 3;
            bhreg[i] = *(const uint4*)&Bh_g[(size_t)row * KTOT + k0 + kk];
            blreg[i] = *(const uint4*)&Bl_g[(size_t)row * KTOT + k0 + kk];
        }
    };

    auto stage_lds = [&]() {
#pragma unroll
        for (int i = 0; i < 4; ++i) {
            int v = tid + i * 256;
            int row = v >> 3;
            int kk = (v & 7) << 2;
            float4 val = areg[i];
            // truncated hi-split; lo captures the residual (trunc too: err ~2^-16)
            unsigned h01 = pack_hi(val.x, val.y);
            unsigned h23 = pack_hi(val.z, val.w);
            float r0 = val.x - zlow(val.x), r1 = val.y - zlow(val.y);
            float r2 = val.z - zlow(val.z), r3 = val.w - zlow(val.w);
            unsigned l01 = pack_hi(r0, r1);
            unsigned l23 = pack_hi(r2, r3);
            *(uint2*)&Ah[row][kk] = make_uint2(h01, h23);
            *(uint2*)&Al[row][kk] = make_uint2(l01, l23);
        }
#pragma unroll
        for (int i = 0; i < BV; ++i) {
            int v = tid + i * 256;
            int row = v >> 2;
            int kk = (v & 3) << 3;
            *(uint4*)&Bh[row][kk] = bhreg[i];
            *(uint4*)&Bl[row][kk] = blreg[i];
        }
    };

    load_chunk(0);
    for (int k0 = 0; k0 < KTOT; k0 += KC) {
        stage_lds();
        __syncthreads();
        if (k0 + KC < KTOT) load_chunk(k0 + KC);  // prefetch overlaps MFMA below

        int kb = q * 8;
        bf16x8 a_h[2], a_l[2];
#pragma unroll
        for (int mt = 0; mt < 2; ++mt) {
            int r = wave * 32 + mt * 16 + lm;
            a_h[mt] = *(const bf16x8*)&Ah[r][kb];
            a_l[mt] = *(const bf16x8*)&Al[r][kb];
        }
#pragma unroll
        for (int nt = 0; nt < NT; ++nt) {
            int c = nt * 16 + lm;
            bf16x8 b_h = *(const bf16x8*)&Bh[c][kb];
            bf16x8 b_l = *(const bf16x8*)&Bl[c][kb];
#pragma unroll
            for (int mt = 0; mt < 2; ++mt) {
                acc[mt][nt] = __builtin_amdgcn_mfma_f32_16x16x32_bf16(a_h[mt], b_h, acc[mt][nt], 0, 0, 0);
                acc[mt][nt] = __builtin_amdgcn_mfma_f32_16x16x32_bf16(a_h[mt], b_l, acc[mt][nt], 0, 0, 0);
                acc[mt][nt] = __builtin_amdgcn_mfma_f32_16x16x32_bf16(a_l[mt], b_h, acc[mt][nt], 0, 0, 0);
            }
        }
        __syncthreads();
    }

#pragma unroll
    for (int mt = 0; mt < 2; ++mt) {
#pragma unroll
        for (int i = 0; i < 4; ++i) {
            int r = m0 + wave * 32 + mt * 16 + q * 4 + i;
            if (r < M) {
                float dv = dinv[r];
#pragma unroll
                for (int nt = 0; nt < NT; ++nt) {
                    C[(size_t)r * BN + nt * 16 + lm] = (_Float16)(acc[mt][nt][i] * dv);
                }
            }
        }
    }
}

// ---------------- aggregation (fp16 gather, fp32 accumulate) ----------------
__global__ __launch_bounds__(256) void agg_f2h(const __half2* __restrict__ g,
                                               const int* __restrict__ rowptr,
                                               const int* __restrict__ colarr,
                                               const float* __restrict__ dinv,
                                               const float* __restrict__ bias,
                                               float2* __restrict__ out, int n) {
    int node = blockIdx.x * 4 + (threadIdx.x >> 6);
    int lane = threadIdx.x & 63;
    if (node >= n) return;
    int beg = rowptr[node];
    int end = rowptr[node + 1];
    float2 acc = __half22float2(g[(size_t)node * 64 + lane]);
    int p = beg;
    for (; p + 4 <= end; p += 4) {
        int s0 = colarr[p], s1 = colarr[p + 1], s2 = colarr[p + 2], s3 = colarr[p + 3];
        float2 v0 = __half22float2(g[(size_t)s0 * 64 + lane]);
        float2 v1 = __half22float2(g[(size_t)s1 * 64 + lane]);
        float2 v2 = __half22float2(g[(size_t)s2 * 64 + lane]);
        float2 v3 = __half22float2(g[(size_t)s3 * 64 + lane]);
        acc.x += (v0.x + v1.x) + (v2.x + v3.x);
        acc.y += (v0.y + v1.y) + (v2.y + v3.y);
    }
    for (; p < end; ++p) {
        float2 v = __half22float2(g[(size_t)colarr[p] * 64 + lane]);
        acc.x += v.x;
        acc.y += v.y;
    }
    float dv = dinv[node];
    float2 b = ((const float2*)bias)[lane];
    float2 o;
    o.x = fmaxf(fmaf(acc.x, dv, b.x), 0.f);
    o.y = fmaxf(fmaf(acc.y, dv, b.y), 0.f);
    out[(size_t)node * 64 + lane] = o;
}

__global__ __launch_bounds__(256) void agg_f1h(const _Float16* __restrict__ g,
                                               const int* __restrict__ rowptr,
                                               const int* __restrict__ colarr,
                                               const float* __restrict__ dinv,
                                               const float* __restrict__ bias,
                                               float* __restrict__ out, int n) {
    int node = blockIdx.x * 4 + (threadIdx.x >> 6);
    int lane = threadIdx.x & 63;
    if (node >= n) return;
    int beg = rowptr[node];
    int end = rowptr[node + 1];
    float acc = (float)g[(size_t)node * 64 + lane];
    int p = beg;
    for (; p + 4 <= end; p += 4) {
        int s0 = colarr[p], s1 = colarr[p + 1], s2 = colarr[p + 2], s3 = colarr[p + 3];
        float v0 = (float)g[(size_t)s0 * 64 + lane];
        float v1 = (float)g[(size_t)s1 * 64 + lane];
        float v2 = (float)g[(size_t)s2 * 64 + lane];
        float v3 = (float)g[(size_t)s3 * 64 + lane];
        acc += (v0 + v1) + (v2 + v3);
    }
    for (; p < end; ++p) acc += (float)g[(size_t)colarr[p] * 64 + lane];
    float dv = dinv[node];
    float o = fmaxf(fmaf(acc, dv, bias[lane]), 0.f);
    out[(size_t)node * 64 + lane] = o;
}

extern "C" void kernel_launch(void* const* d_in, const int* in_sizes, int n_in,
                              void* d_out, int out_size, void* d_ws, size_t ws_size,
                              hipStream_t stream) {
    const float* x  = (const float*)d_in[0];
    const int*   ei = (const int*)d_in[1];
    const float* W1 = (const float*)d_in[2];
    const float* b1 = (const float*)d_in[3];
    const float* W2 = (const float*)d_in[4];
    const float* b2 = (const float*)d_in[5];
    float* out = (float*)d_out;

    const int E = in_sizes[1] / 2;
    const int H1 = in_sizes[3];                 // 128
    const int K1 = in_sizes[2] / H1;            // 256
    const int N = in_sizes[0] / K1;             // 100000
    const int H2 = in_sizes[4] / H1;            // 64
    const int* src = ei;
    const int* dst = ei + E;
    const int NB = (N + 255) >> 8;

    char* ws = (char*)d_ws;
    ushort*   w1th   = (ushort*)(ws + OFF_W1TH);
    ushort*   w1tl   = (ushort*)(ws + OFF_W1TL);
    ushort*   w2th   = (ushort*)(ws + OFF_W2TH);
    ushort*   w2tl   = (ushort*)(ws + OFF_W2TL);
    int*      bcnt   = (int*)(ws + OFF_BCNT);
    int*      bbase  = (int*)(ws + OFF_BBASE);
    int*      bcur   = (int*)(ws + OFF_BCUR);
    int*      rowptr = (int*)(ws + OFF_ROWPTR);
    float*    dinv   = (float*)(ws + OFF_DINV);
    int*      colarr = (int*)(ws + OFF_COL);
    int2*     ebuf   = (int2*)(ws + OFF_EBUF);
    _Float16* h1g    = (_Float16*)(ws + OFF_H1G);
    float*    h1out  = (float*)(ws + OFF_H1OUT);
    _Float16* h2g    = (_Float16*)(ws + OFF_H1G);   // reuse

    hipMemsetAsync(bcnt, 0, 512 * sizeof(int), stream);
    bincount<<<256, 256, 0, stream>>>(dst, bcnt, E);
    bscan<<<1, 512, 0, stream>>>(bcnt, bbase, bcur, rowptr, NB, N, E);
    binscatter<<<(E + CHUNK - 1) / CHUNK, 256, 0, stream>>>(src, dst, bcur, ebuf, E);
    buildcsr<<<NB, 256, 0, stream>>>(ebuf, bbase, bcnt, rowptr, colarr, dinv, N);

    split_wt<<<(K1 * H1 + 255) / 256, 256, 0, stream>>>(W1, w1th, w1tl, K1, H1);
    split_wt<<<(H1 * H2 + 255) / 256, 256, 0, stream>>>(W2, w2th, w2tl, H1, H2);

    // layer 1
    gemm_mfma<128, 256><<<(N + 127) / 128, 256, 0, stream>>>(x, w1th, w1tl, dinv, h1g, N);
    agg_f2h<<<(N + 3) / 4, 256, 0, stream>>>((const __half2*)h1g, rowptr, colarr, dinv, b1,
                                             (float2*)h1out, N);

    // layer 2
    gemm_mfma<64, 128><<<(N + 127) / 128, 256, 0, stream>>>(h1out, w2th, w2tl, dinv, h2g, N);
    agg_f1h<<<(N + 3) / 4, 256, 0, stream>>>(h2g, rowptr, colarr, dinv, b2, out, N);
}

// Round 6
// 409.590 us; speedup vs baseline: 1.1015x; 1.1015x over previous
//
#include <hip/hip_runtime.h>
#include <hip/hip_fp16.h>

// ---------------- problem constants ----------------
#define NNODES 100000

// ---------------- workspace layout (bytes) ----------------
#define OFF_W1TH     0UL            // _Float16[256*128] frag-order = 65536
#define OFF_W1TL     65536UL        // _Float16[256*128]
#define OFF_W2TH     131072UL       // _Float16[128*64] = 16384
#define OFF_W2TL     147456UL       // _Float16[128*64] -> ends 163840
#define OFF_BCNT     163840UL       // int[512]
#define OFF_BBASE    165888UL       // int[512]
#define OFF_BCUR     167936UL       // int[512] -> ends 169984
#define OFF_ROWPTR   400128UL       // int[100001]
#define OFF_DINV     1200640UL      // float[100000]
#define OFF_COL      1605632UL      // int[1600000]  -> ends 8005632
#define OFF_EBUF     8005632UL      // int2[1600000] = 12.8MB (overlaps h1g; dead before gemm1)
#define OFF_H1G      8005632UL      // half[100000*128] = 25.6MB -> ends 33605632
#define OFF_H1OUT    59205632UL     // half[100000*128] = 25.6MB -> ends 84805632
// h2g (half[100000*64]) reuses OFF_H1G (h1g dead after agg1)

typedef __attribute__((ext_vector_type(8))) _Float16 f16x8;
typedef __attribute__((ext_vector_type(4))) float f32x4;

// async global->LDS 16B per lane (dest = wave-uniform base + lane*16)
__device__ __forceinline__ void async_copy16(void* lds, const void* g) {
    __builtin_amdgcn_global_load_lds(
        (const __attribute__((address_space(1))) unsigned*)g,
        (__attribute__((address_space(3))) unsigned*)lds, 16, 0, 0);
}

// =========== CSR build via 2-level counting sort (bucket = dst>>8) ===========
__global__ __launch_bounds__(256) void bincount(const int* __restrict__ dst,
                                                int* __restrict__ bcnt, int E) {
    __shared__ int lc[512];
    int t = threadIdx.x;
    lc[t] = 0; lc[t + 256] = 0;
    __syncthreads();
    for (int e = blockIdx.x * 256 + t; e < E; e += gridDim.x * 256)
        atomicAdd(&lc[dst[e] >> 8], 1);
    __syncthreads();
    if (lc[t]) atomicAdd(&bcnt[t], lc[t]);
    if (lc[t + 256]) atomicAdd(&bcnt[t + 256], lc[t + 256]);
}

__global__ __launch_bounds__(512) void bscan(const int* __restrict__ bcnt,
                                             int* __restrict__ bbase,
                                             int* __restrict__ bcur,
                                             int* __restrict__ rowptr,
                                             int NB, int N, int E) {
    __shared__ int s[512];
    int t = threadIdx.x;
    int v = (t < NB) ? bcnt[t] : 0;
    s[t] = v;
    __syncthreads();
    for (int off = 1; off < 512; off <<= 1) {
        int add = (t >= off) ? s[t - off] : 0;
        __syncthreads();
        s[t] += add;
        __syncthreads();
    }
    if (t < NB) {
        int ex = s[t] - v;
        bbase[t] = ex;
        bcur[t] = ex;
    }
    if (t == 0) rowptr[N] = E;
}

#define CHUNK 4096
__global__ __launch_bounds__(256) void binscatter(const int* __restrict__ src,
                                                  const int* __restrict__ dst,
                                                  int* __restrict__ bcur,
                                                  int2* __restrict__ ebuf, int E) {
    __shared__ int lc[512];
    __shared__ int gb[512];
    int t = threadIdx.x;
    lc[t] = 0; lc[t + 256] = 0;
    __syncthreads();
    int base = blockIdx.x * CHUNK;
    int rb[16];
#pragma unroll
    for (int i = 0; i < 16; ++i) {
        int e = base + i * 256 + t;
        if (e < E) {
            int b = dst[e] >> 8;
            rb[i] = (b << 12) | atomicAdd(&lc[b], 1);
        } else rb[i] = -1;
    }
    __syncthreads();
    if (lc[t]) gb[t] = atomicAdd(&bcur[t], lc[t]);
    if (lc[t + 256]) gb[t + 256] = atomicAdd(&bcur[t + 256], lc[t + 256]);
    __syncthreads();
#pragma unroll
    for (int i = 0; i < 16; ++i) {
        if (rb[i] >= 0) {
            int e = base + i * 256 + t;
            int b = rb[i] >> 12, r = rb[i] & 4095;
            ebuf[gb[b] + r] = make_int2(src[e], dst[e]);
        }
    }
}

__global__ __launch_bounds__(256) void buildcsr(const int2* __restrict__ ebuf,
                                                const int* __restrict__ bbase,
                                                const int* __restrict__ bcnt,
                                                int* __restrict__ rowptr,
                                                int* __restrict__ colarr,
                                                float* __restrict__ dinv, int N) {
    int b = blockIdx.x;
    int t = threadIdx.x;
    int start = bbase[b];
    int cnt = bcnt[b];
    int n0 = b << 8;
    __shared__ int nc[256];
    __shared__ int s[256];
    __shared__ int ncur[256];
    nc[t] = 0;
    __syncthreads();
    for (int e = t; e < cnt; e += 256) atomicAdd(&nc[ebuf[start + e].y - n0], 1);
    __syncthreads();
    int own = nc[t];
    s[t] = own;
    __syncthreads();
    for (int off = 1; off < 256; off <<= 1) {
        int add = (t >= off) ? s[t - off] : 0;
        __syncthreads();
        s[t] += add;
        __syncthreads();
    }
    int rowbase = start + s[t] - own;
    if (n0 + t < N) {
        rowptr[n0 + t] = rowbase;
        dinv[n0 + t] = rsqrtf((float)(own + 1));
    }
    ncur[t] = rowbase;
    __syncthreads();
    for (int e = t; e < cnt; e += 256) {
        int2 p = ebuf[start + e];
        int slot = atomicAdd(&ncur[p.y - n0], 1);
        colarr[slot] = p.x;
    }
}

// ------- split W [K][N] fp32 -> fp16 hi/lo in MFMA FRAGMENT ORDER -------
// frag id f = kc*NT + nt (kc = k-chunk of 32, nt = 16-col tile); element
// (lane l, j): W[k = kc*32 + (l>>4)*8 + j][n = nt*16 + (l&15)]
// flat idx = f*512 + l*8 + j
__global__ __launch_bounds__(256) void split_wt_frag(const float* __restrict__ W,
                                                     _Float16* __restrict__ hi,
                                                     _Float16* __restrict__ lo,
                                                     int K, int N) {
    int idx = blockIdx.x * 256 + threadIdx.x;
    if (idx >= K * N) return;
    int NT = N >> 4;
    int j = idx & 7;
    int l = (idx >> 3) & 63;
    int f = idx >> 9;
    int nt = f % NT;
    int kc = f / NT;
    int k = kc * 32 + (l >> 4) * 8 + j;
    int n = nt * 16 + (l & 15);
    float v = W[k * N + n];
    _Float16 h = (_Float16)v;
    hi[idx] = h;
    lo[idx] = (_Float16)(v - (float)h);
}

// ---------------- fp16 MFMA GEMM (A fp32->fp16 cast or native fp16) ----------------
// C[m][n] = (sum_k A[m][k] * W[k][n]) * dinv[m], stored fp16.
// block 256 thr = 4 waves, tile 128 x BN; KC=64 per iter (2 k-chunks of 32).
// B staged via global_load_lds from fragment-ordered tables (no VGPR, no VALU).
// LDS: A 18.4KB + B 2*NT*2KB  (BN=128: 51.2KB -> 3 blk/CU; BN=64: 34.8KB -> 4)
template <int BN, int KTOT, bool AFP16>
__global__ __launch_bounds__(256, 3) void gemm_f16(const void* __restrict__ Araw,
                                                   const _Float16* __restrict__ Bh_g,
                                                   const _Float16* __restrict__ Bl_g,
                                                   const float* __restrict__ dinv,
                                                   _Float16* __restrict__ C, int M) {
    constexpr int NT = BN / 16;
    constexpr int FPW = (2 * NT) / 4;  // B frags per wave per table per K-iter
    __shared__ _Float16 Ah[128][72];   // 144B rows: 16B-aligned, 2-way alias free
    __shared__ _Float16 Bsh[2 * NT * 512];
    __shared__ _Float16 Bsl[2 * NT * 512];

    const int tid = threadIdx.x;
    const int wave = tid >> 6;
    const int lane = tid & 63;
    const int lm = lane & 15;
    const int q = lane >> 4;
    const int m0 = blockIdx.x * 128;

    f32x4 acc[2][NT];
#pragma unroll
    for (int a = 0; a < 2; ++a)
#pragma unroll
        for (int b = 0; b < NT; ++b) acc[a][b] = (f32x4){0.f, 0.f, 0.f, 0.f};

    for (int k0 = 0; k0 < KTOT; k0 += 64) {
        // ---- B: async DMA, fragment-ordered, contiguous ----
        const int kc0 = k0 >> 5;
        const _Float16* bh_base = Bh_g + (size_t)kc0 * NT * 512;
        const _Float16* bl_base = Bl_g + (size_t)kc0 * NT * 512;
#pragma unroll
        for (int i = 0; i < FPW; ++i) {
            int f = wave * FPW + i;
            async_copy16(&Bsh[f * 512 + lane * 8], bh_base + f * 512 + lane * 8);
            async_copy16(&Bsl[f * 512 + lane * 8], bl_base + f * 512 + lane * 8);
        }
        // ---- A: 128 x 64, VGPR round-trip (cast to fp16 if needed) ----
#pragma unroll
        for (int i = 0; i < 4; ++i) {
            int flat = tid + i * 256;      // 1024 slots of 8 elems
            int row = flat >> 3;
            int kk = (flat & 7) << 3;
            int gr = m0 + row;
            if (AFP16) {
                uint4 hv = make_uint4(0u, 0u, 0u, 0u);
                if (gr < M)
                    hv = *(const uint4*)&((const _Float16*)Araw)[(size_t)gr * KTOT + k0 + kk];
                *(uint4*)&Ah[row][kk] = hv;
            } else {
                const float* Af = (const float*)Araw;
                float4 v0 = make_float4(0.f, 0.f, 0.f, 0.f);
                float4 v1 = make_float4(0.f, 0.f, 0.f, 0.f);
                if (gr < M) {
                    v0 = *(const float4*)&Af[(size_t)gr * KTOT + k0 + kk];
                    v1 = *(const float4*)&Af[(size_t)gr * KTOT + k0 + kk + 4];
                }
                f16x8 h;
                h[0] = (_Float16)v0.x; h[1] = (_Float16)v0.y;
                h[2] = (_Float16)v0.z; h[3] = (_Float16)v0.w;
                h[4] = (_Float16)v1.x; h[5] = (_Float16)v1.y;
                h[6] = (_Float16)v1.z; h[7] = (_Float16)v1.w;
                *(f16x8*)&Ah[row][kk] = h;
            }
        }
        __syncthreads();  // drains lgkm + vmcnt (incl. global_load_lds)

#pragma unroll
        for (int dkc = 0; dkc < 2; ++dkc) {
            f16x8 a[2];
#pragma unroll
            for (int mt = 0; mt < 2; ++mt)
                a[mt] = *(const f16x8*)&Ah[wave * 32 + mt * 16 + lm][dkc * 32 + q * 8];
#pragma unroll
            for (int nt = 0; nt < NT; ++nt) {
                f16x8 bh = *(const f16x8*)&Bsh[(dkc * NT + nt) * 512 + lane * 8];
                f16x8 bl = *(const f16x8*)&Bsl[(dkc * NT + nt) * 512 + lane * 8];
#pragma unroll
                for (int mt = 0; mt < 2; ++mt) {
                    acc[mt][nt] = __builtin_amdgcn_mfma_f32_16x16x32_f16(a[mt], bh, acc[mt][nt], 0, 0, 0);
                    acc[mt][nt] = __builtin_amdgcn_mfma_f32_16x16x32_f16(a[mt], bl, acc[mt][nt], 0, 0, 0);
                }
            }
        }
        __syncthreads();
    }

    // ---- epilogue: scale by dinv[row], store fp16 ----
#pragma unroll
    for (int mt = 0; mt < 2; ++mt) {
#pragma unroll
        for (int i = 0; i < 4; ++i) {
            int r = m0 + wave * 32 + mt * 16 + q * 4 + i;
            if (r < M) {
                float dv = dinv[r];
#pragma unroll
                for (int nt = 0; nt < NT; ++nt) {
                    C[(size_t)r * BN + nt * 16 + lm] = (_Float16)(acc[mt][nt][i] * dv);
                }
            }
        }
    }
}

// ---------------- aggregation (fp16 gather, fp32 accumulate) ----------------
// 128 ch: one wave per node, half2 per lane; OUT fp16 (feeds gemm2)
__global__ __launch_bounds__(256) void agg_f2h(const __half2* __restrict__ g,
                                               const int* __restrict__ rowptr,
                                               const int* __restrict__ colarr,
                                               const float* __restrict__ dinv,
                                               const float* __restrict__ bias,
                                               __half2* __restrict__ out, int n) {
    int node = blockIdx.x * 4 + (threadIdx.x >> 6);
    int lane = threadIdx.x & 63;
    if (node >= n) return;
    int beg = rowptr[node];
    int end = rowptr[node + 1];
    float2 acc = __half22float2(g[(size_t)node * 64 + lane]);
    int p = beg;
    for (; p + 4 <= end; p += 4) {
        int s0 = colarr[p], s1 = colarr[p + 1], s2 = colarr[p + 2], s3 = colarr[p + 3];
        float2 v0 = __half22float2(g[(size_t)s0 * 64 + lane]);
        float2 v1 = __half22float2(g[(size_t)s1 * 64 + lane]);
        float2 v2 = __half22float2(g[(size_t)s2 * 64 + lane]);
        float2 v3 = __half22float2(g[(size_t)s3 * 64 + lane]);
        acc.x += (v0.x + v1.x) + (v2.x + v3.x);
        acc.y += (v0.y + v1.y) + (v2.y + v3.y);
    }
    for (; p < end; ++p) {
        float2 v = __half22float2(g[(size_t)colarr[p] * 64 + lane]);
        acc.x += v.x;
        acc.y += v.y;
    }
    float dv = dinv[node];
    float2 b = ((const float2*)bias)[lane];
    float ox = fmaxf(fmaf(acc.x, dv, b.x), 0.f);
    float oy = fmaxf(fmaf(acc.y, dv, b.y), 0.f);
    out[(size_t)node * 64 + lane] = __floats2half2_rn(ox, oy);
}

// 64 ch: one wave per node, one half per lane; out fp32 (final output)
__global__ __launch_bounds__(256) void agg_f1h(const _Float16* __restrict__ g,
                                               const int* __restrict__ rowptr,
                                               const int* __restrict__ colarr,
                                               const float* __restrict__ dinv,
                                               const float* __restrict__ bias,
                                               float* __restrict__ out, int n) {
    int node = blockIdx.x * 4 + (threadIdx.x >> 6);
    int lane = threadIdx.x & 63;
    if (node >= n) return;
    int beg = rowptr[node];
    int end = rowptr[node + 1];
    float acc = (float)g[(size_t)node * 64 + lane];
    int p = beg;
    for (; p + 4 <= end; p += 4) {
        int s0 = colarr[p], s1 = colarr[p + 1], s2 = colarr[p + 2], s3 = colarr[p + 3];
        float v0 = (float)g[(size_t)s0 * 64 + lane];
        float v1 = (float)g[(size_t)s1 * 64 + lane];
        float v2 = (float)g[(size_t)s2 * 64 + lane];
        float v3 = (float)g[(size_t)s3 * 64 + lane];
        acc += (v0 + v1) + (v2 + v3);
    }
    for (; p < end; ++p) acc += (float)g[(size_t)colarr[p] * 64 + lane];
    float dv = dinv[node];
    float o = fmaxf(fmaf(acc, dv, bias[lane]), 0.f);
    out[(size_t)node * 64 + lane] = o;
}

extern "C" void kernel_launch(void* const* d_in, const int* in_sizes, int n_in,
                              void* d_out, int out_size, void* d_ws, size_t ws_size,
                              hipStream_t stream) {
    const float* x  = (const float*)d_in[0];
    const int*   ei = (const int*)d_in[1];
    const float* W1 = (const float*)d_in[2];
    const float* b1 = (const float*)d_in[3];
    const float* W2 = (const float*)d_in[4];
    const float* b2 = (const float*)d_in[5];
    float* out = (float*)d_out;

    const int E = in_sizes[1] / 2;
    const int H1 = in_sizes[3];                 // 128
    const int K1 = in_sizes[2] / H1;            // 256
    const int N = in_sizes[0] / K1;             // 100000
    const int H2 = in_sizes[4] / H1;            // 64
    const int* src = ei;
    const int* dst = ei + E;
    const int NB = (N + 255) >> 8;

    char* ws = (char*)d_ws;
    _Float16* w1th   = (_Float16*)(ws + OFF_W1TH);
    _Float16* w1tl   = (_Float16*)(ws + OFF_W1TL);
    _Float16* w2th   = (_Float16*)(ws + OFF_W2TH);
    _Float16* w2tl   = (_Float16*)(ws + OFF_W2TL);
    int*      bcnt   = (int*)(ws + OFF_BCNT);
    int*      bbase  = (int*)(ws + OFF_BBASE);
    int*      bcur   = (int*)(ws + OFF_BCUR);
    int*      rowptr = (int*)(ws + OFF_ROWPTR);
    float*    dinv   = (float*)(ws + OFF_DINV);
    int*      colarr = (int*)(ws + OFF_COL);
    int2*     ebuf   = (int2*)(ws + OFF_EBUF);
    _Float16* h1g    = (_Float16*)(ws + OFF_H1G);
    _Float16* h1out  = (_Float16*)(ws + OFF_H1OUT);
    _Float16* h2g    = (_Float16*)(ws + OFF_H1G);   // reuse

    hipMemsetAsync(bcnt, 0, 512 * sizeof(int), stream);
    bincount<<<256, 256, 0, stream>>>(dst, bcnt, E);
    bscan<<<1, 512, 0, stream>>>(bcnt, bbase, bcur, rowptr, NB, N, E);
    binscatter<<<(E + CHUNK - 1) / CHUNK, 256, 0, stream>>>(src, dst, bcur, ebuf, E);
    buildcsr<<<NB, 256, 0, stream>>>(ebuf, bbase, bcnt, rowptr, colarr, dinv, N);

    split_wt_frag<<<(K1 * H1 + 255) / 256, 256, 0, stream>>>(W1, w1th, w1tl, K1, H1);
    split_wt_frag<<<(H1 * H2 + 255) / 256, 256, 0, stream>>>(W2, w2th, w2tl, H1, H2);

    // layer 1: A = x (fp32 cast to fp16 in staging)
    gemm_f16<128, 256, false><<<(N + 127) / 128, 256, 0, stream>>>(x, w1th, w1tl, dinv, h1g, N);
    agg_f2h<<<(N + 3) / 4, 256, 0, stream>>>((const __half2*)h1g, rowptr, colarr, dinv, b1,
                                             (__half2*)h1out, N);

    // layer 2: A = h1out (native fp16)
    gemm_f16<64, 128, true><<<(N + 127) / 128, 256, 0, stream>>>(h1out, w2th, w2tl, dinv, h2g, N);
    agg_f1h<<<(N + 3) / 4, 256, 0, stream>>>(h2g, rowptr, colarr, dinv, b2, out, N);
}

// Round 7
// 384.164 us; speedup vs baseline: 1.1744x; 1.0662x over previous
//
#include <hip/hip_runtime.h>
#include <hip/hip_fp16.h>

// ---------------- problem constants ----------------
#define NNODES 100000

// ---------------- workspace layout (bytes) ----------------
#define OFF_W1TH     0UL            // _Float16[256*128] frag-order = 65536
#define OFF_W1TL     65536UL        // _Float16[256*128]
#define OFF_W2TH     131072UL       // _Float16[128*64] = 16384
#define OFF_W2TL     147456UL       // _Float16[128*64] -> ends 163840
#define OFF_BCNT     163840UL       // int[512]
#define OFF_BBASE    165888UL       // int[512]
#define OFF_BCUR     167936UL       // int[512] -> ends 169984
#define OFF_ROWPTR   400128UL       // int[100001]
#define OFF_DINV     1200640UL      // float[100000]
#define OFF_COL      1605632UL      // int[1600000]  -> ends 8005632
#define OFF_EBUF     8005632UL      // int[1600000] = 6.4MB (overlaps h1g; dead before gemm1)
#define OFF_H1G      8005632UL      // half[100000*128] = 25.6MB -> ends 33605632
#define OFF_H1OUT    59205632UL     // half[100000*128] = 25.6MB -> ends 84805632
// h2g (half[100000*64]) reuses OFF_H1G (h1g dead after agg1)

typedef __attribute__((ext_vector_type(8))) _Float16 f16x8;
typedef __attribute__((ext_vector_type(4))) float f32x4;

// async global->LDS 16B per lane (dest = wave-uniform base + lane*16)
__device__ __forceinline__ void async_copy16(void* lds, const void* g) {
    __builtin_amdgcn_global_load_lds(
        (const __attribute__((address_space(1))) unsigned*)g,
        (__attribute__((address_space(3))) unsigned*)lds, 16, 0, 0);
}

// =========== CSR build via 2-level counting sort (bucket = dst>>8) ===========
__global__ __launch_bounds__(256) void bincount(const int* __restrict__ dst,
                                                int* __restrict__ bcnt, int E) {
    __shared__ int lc[512];
    int t = threadIdx.x;
    lc[t] = 0; lc[t + 256] = 0;
    __syncthreads();
    for (int e = blockIdx.x * 256 + t; e < E; e += gridDim.x * 256)
        atomicAdd(&lc[dst[e] >> 8], 1);
    __syncthreads();
    if (lc[t]) atomicAdd(&bcnt[t], lc[t]);
    if (lc[t + 256]) atomicAdd(&bcnt[t + 256], lc[t + 256]);
}

__global__ __launch_bounds__(512) void bscan(const int* __restrict__ bcnt,
                                             int* __restrict__ bbase,
                                             int* __restrict__ bcur,
                                             int* __restrict__ rowptr,
                                             int NB, int N, int E) {
    __shared__ int s[512];
    int t = threadIdx.x;
    int v = (t < NB) ? bcnt[t] : 0;
    s[t] = v;
    __syncthreads();
    for (int off = 1; off < 512; off <<= 1) {
        int add = (t >= off) ? s[t - off] : 0;
        __syncthreads();
        s[t] += add;
        __syncthreads();
    }
    if (t < NB) {
        int ex = s[t] - v;
        bbase[t] = ex;
        bcur[t] = ex;
    }
    if (t == 0) rowptr[N] = E;
}

// Phase C: bucket-grouped scatter. Packs (src | localdst<<20) into one int.
#define CHUNK 8192
__global__ __launch_bounds__(256) void binscatter(const int* __restrict__ src,
                                                  const int* __restrict__ dst,
                                                  int* __restrict__ bcur,
                                                  int* __restrict__ ebuf, int E) {
    __shared__ int lc[512];
    __shared__ int gb[512];
    int t = threadIdx.x;
    lc[t] = 0; lc[t + 256] = 0;
    __syncthreads();
    int base = blockIdx.x * CHUNK;
    int rb[32];
#pragma unroll
    for (int i = 0; i < 32; ++i) {
        int e = base + i * 256 + t;
        if (e < E) {
            int b = dst[e] >> 8;
            rb[i] = (b << 13) | atomicAdd(&lc[b], 1);  // rank < 8192 fits 13 bits
        } else rb[i] = -1;
    }
    __syncthreads();
    if (lc[t]) gb[t] = atomicAdd(&bcur[t], lc[t]);
    if (lc[t + 256]) gb[t + 256] = atomicAdd(&bcur[t + 256], lc[t + 256]);
    __syncthreads();
#pragma unroll
    for (int i = 0; i < 32; ++i) {
        if (rb[i] >= 0) {
            int e = base + i * 256 + t;
            int b = rb[i] >> 13, r = rb[i] & 8191;
            ebuf[gb[b] + r] = src[e] | ((dst[e] & 255) << 20);
        }
    }
}

__global__ __launch_bounds__(256) void buildcsr(const int* __restrict__ ebuf,
                                                const int* __restrict__ bbase,
                                                const int* __restrict__ bcnt,
                                                int* __restrict__ rowptr,
                                                int* __restrict__ colarr,
                                                float* __restrict__ dinv, int N) {
    int b = blockIdx.x;
    int t = threadIdx.x;
    int start = bbase[b];
    int cnt = bcnt[b];
    __shared__ int nc[256];
    __shared__ int s[256];
    __shared__ int ncur[256];
    nc[t] = 0;
    __syncthreads();
    for (int e = t; e < cnt; e += 256) atomicAdd(&nc[ebuf[start + e] >> 20], 1);
    __syncthreads();
    int own = nc[t];
    s[t] = own;
    __syncthreads();
    for (int off = 1; off < 256; off <<= 1) {
        int add = (t >= off) ? s[t - off] : 0;
        __syncthreads();
        s[t] += add;
        __syncthreads();
    }
    int rowbase = start + s[t] - own;
    int n0 = b << 8;
    if (n0 + t < N) {
        rowptr[n0 + t] = rowbase;
        dinv[n0 + t] = rsqrtf((float)(own + 1));
    }
    ncur[t] = rowbase;
    __syncthreads();
    for (int e = t; e < cnt; e += 256) {
        int pe = ebuf[start + e];
        int slot = atomicAdd(&ncur[pe >> 20], 1);
        colarr[slot] = pe & 0xFFFFF;
    }
}

// ------- split W [K][N] fp32 -> fp16 hi/lo in MFMA FRAGMENT ORDER -------
__global__ __launch_bounds__(256) void split_wt_frag(const float* __restrict__ W,
                                                     _Float16* __restrict__ hi,
                                                     _Float16* __restrict__ lo,
                                                     int K, int N) {
    int idx = blockIdx.x * 256 + threadIdx.x;
    if (idx >= K * N) return;
    int NT = N >> 4;
    int j = idx & 7;
    int l = (idx >> 3) & 63;
    int f = idx >> 9;
    int nt = f % NT;
    int kc = f / NT;
    int k = kc * 32 + (l >> 4) * 8 + j;
    int n = nt * 16 + (l & 15);
    float v = W[k * N + n];
    _Float16 h = (_Float16)v;
    hi[idx] = h;
    lo[idx] = (_Float16)(v - (float)h);
}

// ---------------- fp16 MFMA GEMM (unchanged from R6) ----------------
template <int BN, int KTOT, bool AFP16>
__global__ __launch_bounds__(256, 3) void gemm_f16(const void* __restrict__ Araw,
                                                   const _Float16* __restrict__ Bh_g,
                                                   const _Float16* __restrict__ Bl_g,
                                                   const float* __restrict__ dinv,
                                                   _Float16* __restrict__ C, int M) {
    constexpr int NT = BN / 16;
    constexpr int FPW = (2 * NT) / 4;
    __shared__ _Float16 Ah[128][72];
    __shared__ _Float16 Bsh[2 * NT * 512];
    __shared__ _Float16 Bsl[2 * NT * 512];

    const int tid = threadIdx.x;
    const int wave = tid >> 6;
    const int lane = tid & 63;
    const int lm = lane & 15;
    const int q = lane >> 4;
    const int m0 = blockIdx.x * 128;

    f32x4 acc[2][NT];
#pragma unroll
    for (int a = 0; a < 2; ++a)
#pragma unroll
        for (int b = 0; b < NT; ++b) acc[a][b] = (f32x4){0.f, 0.f, 0.f, 0.f};

    for (int k0 = 0; k0 < KTOT; k0 += 64) {
        const int kc0 = k0 >> 5;
        const _Float16* bh_base = Bh_g + (size_t)kc0 * NT * 512;
        const _Float16* bl_base = Bl_g + (size_t)kc0 * NT * 512;
#pragma unroll
        for (int i = 0; i < FPW; ++i) {
            int f = wave * FPW + i;
            async_copy16(&Bsh[f * 512 + lane * 8], bh_base + f * 512 + lane * 8);
            async_copy16(&Bsl[f * 512 + lane * 8], bl_base + f * 512 + lane * 8);
        }
#pragma unroll
        for (int i = 0; i < 4; ++i) {
            int flat = tid + i * 256;
            int row = flat >> 3;
            int kk = (flat & 7) << 3;
            int gr = m0 + row;
            if (AFP16) {
                uint4 hv = make_uint4(0u, 0u, 0u, 0u);
                if (gr < M)
                    hv = *(const uint4*)&((const _Float16*)Araw)[(size_t)gr * KTOT + k0 + kk];
                *(uint4*)&Ah[row][kk] = hv;
            } else {
                const float* Af = (const float*)Araw;
                float4 v0 = make_float4(0.f, 0.f, 0.f, 0.f);
                float4 v1 = make_float4(0.f, 0.f, 0.f, 0.f);
                if (gr < M) {
                    v0 = *(const float4*)&Af[(size_t)gr * KTOT + k0 + kk];
                    v1 = *(const float4*)&Af[(size_t)gr * KTOT + k0 + kk + 4];
                }
                f16x8 h;
                h[0] = (_Float16)v0.x; h[1] = (_Float16)v0.y;
                h[2] = (_Float16)v0.z; h[3] = (_Float16)v0.w;
                h[4] = (_Float16)v1.x; h[5] = (_Float16)v1.y;
                h[6] = (_Float16)v1.z; h[7] = (_Float16)v1.w;
                *(f16x8*)&Ah[row][kk] = h;
            }
        }
        __syncthreads();

#pragma unroll
        for (int dkc = 0; dkc < 2; ++dkc) {
            f16x8 a[2];
#pragma unroll
            for (int mt = 0; mt < 2; ++mt)
                a[mt] = *(const f16x8*)&Ah[wave * 32 + mt * 16 + lm][dkc * 32 + q * 8];
#pragma unroll
            for (int nt = 0; nt < NT; ++nt) {
                f16x8 bh = *(const f16x8*)&Bsh[(dkc * NT + nt) * 512 + lane * 8];
                f16x8 bl = *(const f16x8*)&Bsl[(dkc * NT + nt) * 512 + lane * 8];
#pragma unroll
                for (int mt = 0; mt < 2; ++mt) {
                    acc[mt][nt] = __builtin_amdgcn_mfma_f32_16x16x32_f16(a[mt], bh, acc[mt][nt], 0, 0, 0);
                    acc[mt][nt] = __builtin_amdgcn_mfma_f32_16x16x32_f16(a[mt], bl, acc[mt][nt], 0, 0, 0);
                }
            }
        }
        __syncthreads();
    }

#pragma unroll
    for (int mt = 0; mt < 2; ++mt) {
#pragma unroll
        for (int i = 0; i < 4; ++i) {
            int r = m0 + wave * 32 + mt * 16 + q * 4 + i;
            if (r < M) {
                float dv = dinv[r];
#pragma unroll
                for (int nt = 0; nt < NT; ++nt) {
                    C[(size_t)r * BN + nt * 16 + lm] = (_Float16)(acc[mt][nt][i] * dv);
                }
            }
        }
    }
}

// ---------------- aggregation v2: multi-row gathers ----------------
// 128 ch: wave per node; lanes split into 2 groups of 32 -> 2 edges per load
// instruction (512 B/inst). Each lane: 4 fp16 channels (uint2). fp32 accum.
// Final xor-32 butterfly; lanes 0-31 store fp16 (feeds gemm2).
__global__ __launch_bounds__(256) void agg128(const _Float16* __restrict__ g,
                                              const int* __restrict__ rowptr,
                                              const int* __restrict__ colarr,
                                              const float* __restrict__ dinv,
                                              const float* __restrict__ bias,
                                              _Float16* __restrict__ out, int n) {
    int node = blockIdx.x * 4 + (threadIdx.x >> 6);
    int lane = threadIdx.x & 63;
    if (node >= n) return;
    int sel = lane >> 5;        // 0/1: which edge of the pair
    int co = (lane & 31) << 2;  // 4 fp16 channels per lane

    int beg = rowptr[node];
    int end = rowptr[node + 1];

    float a0 = 0.f, a1 = 0.f, a2 = 0.f, a3 = 0.f;
    // self loop: half-wave predicated load
    if (sel == 0) {
        uint2 sv = *(const uint2*)&g[(node << 7) + co];
        float2 f01 = __half22float2(*(const __half2*)&sv.x);
        float2 f23 = __half22float2(*(const __half2*)&sv.y);
        a0 += f01.x; a1 += f01.y; a2 += f23.x; a3 += f23.y;
    }

    int p = beg;
    for (; p + 8 <= end; p += 8) {
        int r0 = colarr[p + sel];
        int r1 = colarr[p + 2 + sel];
        int r2 = colarr[p + 4 + sel];
        int r3 = colarr[p + 6 + sel];
        uint2 v0 = *(const uint2*)&g[(r0 << 7) + co];
        uint2 v1 = *(const uint2*)&g[(r1 << 7) + co];
        uint2 v2 = *(const uint2*)&g[(r2 << 7) + co];
        uint2 v3 = *(const uint2*)&g[(r3 << 7) + co];
#pragma unroll
        for (int i = 0; i < 4; ++i) {
            uint2 v = (i == 0) ? v0 : (i == 1) ? v1 : (i == 2) ? v2 : v3;
            float2 f01 = __half22float2(*(const __half2*)&v.x);
            float2 f23 = __half22float2(*(const __half2*)&v.y);
            a0 += f01.x; a1 += f01.y; a2 += f23.x; a3 += f23.y;
        }
    }
    for (; p + 2 <= end; p += 2) {
        int r = colarr[p + sel];
        uint2 v = *(const uint2*)&g[(r << 7) + co];
        float2 f01 = __half22float2(*(const __half2*)&v.x);
        float2 f23 = __half22float2(*(const __half2*)&v.y);
        a0 += f01.x; a1 += f01.y; a2 += f23.x; a3 += f23.y;
    }
    if (p < end && sel == 0) {  // odd remainder: half-wave
        int r = colarr[p];
        uint2 v = *(const uint2*)&g[(r << 7) + co];
        float2 f01 = __half22float2(*(const __half2*)&v.x);
        float2 f23 = __half22float2(*(const __half2*)&v.y);
        a0 += f01.x; a1 += f01.y; a2 += f23.x; a3 += f23.y;
    }

    // combine the two halves
    a0 += __shfl(a0, lane ^ 32);
    a1 += __shfl(a1, lane ^ 32);
    a2 += __shfl(a2, lane ^ 32);
    a3 += __shfl(a3, lane ^ 32);

    if (sel == 0) {
        float dv = dinv[node];
        float4 b = *(const float4*)&bias[co];
        float o0 = fmaxf(fmaf(a0, dv, b.x), 0.f);
        float o1 = fmaxf(fmaf(a1, dv, b.y), 0.f);
        float o2 = fmaxf(fmaf(a2, dv, b.z), 0.f);
        float o3 = fmaxf(fmaf(a3, dv, b.w), 0.f);
        __half2 ha = __floats2half2_rn(o0, o1);
        __half2 hb = __floats2half2_rn(o2, o3);
        uint2 pk = make_uint2(*(unsigned*)&ha, *(unsigned*)&hb);
        *(uint2*)&out[(node << 7) + co] = pk;
    }
}

// 64 ch: wave per node; 4 groups of 16 lanes -> 4 edges per load instruction.
// Each lane: 4 fp16 channels. Butterfly xor-16, xor-32; lanes 0-15 store fp32.
__global__ __launch_bounds__(256) void agg64(const _Float16* __restrict__ g,
                                             const int* __restrict__ rowptr,
                                             const int* __restrict__ colarr,
                                             const float* __restrict__ dinv,
                                             const float* __restrict__ bias,
                                             float* __restrict__ out, int n) {
    int node = blockIdx.x * 4 + (threadIdx.x >> 6);
    int lane = threadIdx.x & 63;
    if (node >= n) return;
    int sel = lane >> 4;        // 0..3
    int co = (lane & 15) << 2;  // 4 fp16 channels

    int beg = rowptr[node];
    int end = rowptr[node + 1];

    float a0 = 0.f, a1 = 0.f, a2 = 0.f, a3 = 0.f;
    if (sel == 0) {  // self loop: quarter-wave
        uint2 sv = *(const uint2*)&g[(node << 6) + co];
        float2 f01 = __half22float2(*(const __half2*)&sv.x);
        float2 f23 = __half22float2(*(const __half2*)&sv.y);
        a0 += f01.x; a1 += f01.y; a2 += f23.x; a3 += f23.y;
    }

    int p = beg;
    for (; p + 16 <= end; p += 16) {
        int r0 = colarr[p + sel];
        int r1 = colarr[p + 4 + sel];
        int r2 = colarr[p + 8 + sel];
        int r3 = colarr[p + 12 + sel];
        uint2 v0 = *(const uint2*)&g[(r0 << 6) + co];
        uint2 v1 = *(const uint2*)&g[(r1 << 6) + co];
        uint2 v2 = *(const uint2*)&g[(r2 << 6) + co];
        uint2 v3 = *(const uint2*)&g[(r3 << 6) + co];
#pragma unroll
        for (int i = 0; i < 4; ++i) {
            uint2 v = (i == 0) ? v0 : (i == 1) ? v1 : (i == 2) ? v2 : v3;
            float2 f01 = __half22float2(*(const __half2*)&v.x);
            float2 f23 = __half22float2(*(const __half2*)&v.y);
            a0 += f01.x; a1 += f01.y; a2 += f23.x; a3 += f23.y;
        }
    }
    for (; p + 4 <= end; p += 4) {
        int r = colarr[p + sel];
        uint2 v = *(const uint2*)&g[(r << 6) + co];
        float2 f01 = __half22float2(*(const __half2*)&v.x);
        float2 f23 = __half22float2(*(const __half2*)&v.y);
        a0 += f01.x; a1 += f01.y; a2 += f23.x; a3 += f23.y;
    }
    int rem = end - p;
    if (sel < rem) {
        int r = colarr[p + sel];
        uint2 v = *(const uint2*)&g[(r << 6) + co];
        float2 f01 = __half22float2(*(const __half2*)&v.x);
        float2 f23 = __half22float2(*(const __half2*)&v.y);
        a0 += f01.x; a1 += f01.y; a2 += f23.x; a3 += f23.y;
    }

    a0 += __shfl(a0, lane ^ 16); a1 += __shfl(a1, lane ^ 16);
    a2 += __shfl(a2, lane ^ 16); a3 += __shfl(a3, lane ^ 16);
    a0 += __shfl(a0, lane ^ 32); a1 += __shfl(a1, lane ^ 32);
    a2 += __shfl(a2, lane ^ 32); a3 += __shfl(a3, lane ^ 32);

    if (sel == 0) {
        float dv = dinv[node];
        float4 b = *(const float4*)&bias[co];
        float4 o;
        o.x = fmaxf(fmaf(a0, dv, b.x), 0.f);
        o.y = fmaxf(fmaf(a1, dv, b.y), 0.f);
        o.z = fmaxf(fmaf(a2, dv, b.z), 0.f);
        o.w = fmaxf(fmaf(a3, dv, b.w), 0.f);
        *(float4*)&out[(node << 6) + co] = o;
    }
}

extern "C" void kernel_launch(void* const* d_in, const int* in_sizes, int n_in,
                              void* d_out, int out_size, void* d_ws, size_t ws_size,
                              hipStream_t stream) {
    const float* x  = (const float*)d_in[0];
    const int*   ei = (const int*)d_in[1];
    const float* W1 = (const float*)d_in[2];
    const float* b1 = (const float*)d_in[3];
    const float* W2 = (const float*)d_in[4];
    const float* b2 = (const float*)d_in[5];
    float* out = (float*)d_out;

    const int E = in_sizes[1] / 2;
    const int H1 = in_sizes[3];                 // 128
    const int K1 = in_sizes[2] / H1;            // 256
    const int N = in_sizes[0] / K1;             // 100000
    const int H2 = in_sizes[4] / H1;            // 64
    const int* src = ei;
    const int* dst = ei + E;
    const int NB = (N + 255) >> 8;

    char* ws = (char*)d_ws;
    _Float16* w1th   = (_Float16*)(ws + OFF_W1TH);
    _Float16* w1tl   = (_Float16*)(ws + OFF_W1TL);
    _Float16* w2th   = (_Float16*)(ws + OFF_W2TH);
    _Float16* w2tl   = (_Float16*)(ws + OFF_W2TL);
    int*      bcnt   = (int*)(ws + OFF_BCNT);
    int*      bbase  = (int*)(ws + OFF_BBASE);
    int*      bcur   = (int*)(ws + OFF_BCUR);
    int*      rowptr = (int*)(ws + OFF_ROWPTR);
    float*    dinv   = (float*)(ws + OFF_DINV);
    int*      colarr = (int*)(ws + OFF_COL);
    int*      ebuf   = (int*)(ws + OFF_EBUF);
    _Float16* h1g    = (_Float16*)(ws + OFF_H1G);
    _Float16* h1out  = (_Float16*)(ws + OFF_H1OUT);
    _Float16* h2g    = (_Float16*)(ws + OFF_H1G);   // reuse

    hipMemsetAsync(bcnt, 0, 512 * sizeof(int), stream);
    bincount<<<256, 256, 0, stream>>>(dst, bcnt, E);
    bscan<<<1, 512, 0, stream>>>(bcnt, bbase, bcur, rowptr, NB, N, E);
    binscatter<<<(E + CHUNK - 1) / CHUNK, 256, 0, stream>>>(src, dst, bcur, ebuf, E);
    buildcsr<<<NB, 256, 0, stream>>>(ebuf, bbase, bcnt, rowptr, colarr, dinv, N);

    split_wt_frag<<<(K1 * H1 + 255) / 256, 256, 0, stream>>>(W1, w1th, w1tl, K1, H1);
    split_wt_frag<<<(H1 * H2 + 255) / 256, 256, 0, stream>>>(W2, w2th, w2tl, H1, H2);

    // layer 1
    gemm_f16<128, 256, false><<<(N + 127) / 128, 256, 0, stream>>>(x, w1th, w1tl, dinv, h1g, N);
    agg128<<<(N + 3) / 4, 256, 0, stream>>>(h1g, rowptr, colarr, dinv, b1, h1out, N);

    // layer 2
    gemm_f16<64, 128, true><<<(N + 127) / 128, 256, 0, stream>>>(h1out, w2th, w2tl, dinv, h2g, N);
    agg64<<<(N + 3) / 4, 256, 0, stream>>>(h2g, rowptr, colarr, dinv, b2, out, N);
}

// Round 8
// 372.849 us; speedup vs baseline: 1.2101x; 1.0303x over previous
//
#include <hip/hip_runtime.h>
#include <hip/hip_fp16.h>

// ---------------- problem constants ----------------
#define NNODES 100000

// ---------------- workspace layout (bytes) ----------------
#define OFF_W1TH     0UL            // _Float16[256*128] frag-order = 65536
#define OFF_W1TL     65536UL        // _Float16[256*128]
#define OFF_W2TH     131072UL       // _Float16[128*64] = 16384
#define OFF_W2TL     147456UL       // _Float16[128*64] -> ends 163840
#define OFF_BCNT     163840UL       // int[512]
#define OFF_BBASE    165888UL       // int[512]
#define OFF_BCUR     167936UL       // int[512] -> ends 169984
#define OFF_ROWPTR   400128UL       // int[100001]
#define OFF_DINV     1200640UL      // float[100000]
#define OFF_COL      1605632UL      // int[1600000]  -> ends 8005632
#define OFF_EBUF     8005632UL      // int[1600000] = 6.4MB (overlaps h1g; dead before gemm1)
#define OFF_H1G      8005632UL      // half[100000*128] = 25.6MB -> ends 33605632
#define OFF_H1OUT    59205632UL     // half[100000*128] = 25.6MB -> ends 84805632
// h2g (half[100000*64]) reuses OFF_H1G (h1g dead after agg1)

typedef __attribute__((ext_vector_type(8))) _Float16 f16x8;
typedef __attribute__((ext_vector_type(4))) float f32x4;

// async global->LDS 16B per lane (dest = wave-uniform base + lane*16)
__device__ __forceinline__ void async_copy16(void* lds, const void* g) {
    __builtin_amdgcn_global_load_lds(
        (const __attribute__((address_space(1))) unsigned*)g,
        (__attribute__((address_space(3))) unsigned*)lds, 16, 0, 0);
}

// =========== CSR build via 2-level counting sort (bucket = dst>>8) ===========
__global__ __launch_bounds__(256) void bincount(const int* __restrict__ dst,
                                                int* __restrict__ bcnt, int E) {
    __shared__ int lc[512];
    int t = threadIdx.x;
    lc[t] = 0; lc[t + 256] = 0;
    __syncthreads();
    for (int e = blockIdx.x * 256 + t; e < E; e += gridDim.x * 256)
        atomicAdd(&lc[dst[e] >> 8], 1);
    __syncthreads();
    if (lc[t]) atomicAdd(&bcnt[t], lc[t]);
    if (lc[t + 256]) atomicAdd(&bcnt[t + 256], lc[t + 256]);
}

__global__ __launch_bounds__(512) void bscan(const int* __restrict__ bcnt,
                                             int* __restrict__ bbase,
                                             int* __restrict__ bcur,
                                             int* __restrict__ rowptr,
                                             int NB, int N, int E) {
    __shared__ int s[512];
    int t = threadIdx.x;
    int v = (t < NB) ? bcnt[t] : 0;
    s[t] = v;
    __syncthreads();
    for (int off = 1; off < 512; off <<= 1) {
        int add = (t >= off) ? s[t - off] : 0;
        __syncthreads();
        s[t] += add;
        __syncthreads();
    }
    if (t < NB) {
        int ex = s[t] - v;
        bbase[t] = ex;
        bcur[t] = ex;
    }
    if (t == 0) rowptr[N] = E;
}

// Phase C: bucket-grouped scatter. Packs (src | localdst<<20) into one int.
#define CHUNK 8192
__global__ __launch_bounds__(256) void binscatter(const int* __restrict__ src,
                                                  const int* __restrict__ dst,
                                                  int* __restrict__ bcur,
                                                  int* __restrict__ ebuf, int E) {
    __shared__ int lc[512];
    __shared__ int gb[512];
    int t = threadIdx.x;
    lc[t] = 0; lc[t + 256] = 0;
    __syncthreads();
    int base = blockIdx.x * CHUNK;
    int rb[32];
#pragma unroll
    for (int i = 0; i < 32; ++i) {
        int e = base + i * 256 + t;
        if (e < E) {
            int b = dst[e] >> 8;
            rb[i] = (b << 13) | atomicAdd(&lc[b], 1);  // rank < 8192 fits 13 bits
        } else rb[i] = -1;
    }
    __syncthreads();
    if (lc[t]) gb[t] = atomicAdd(&bcur[t], lc[t]);
    if (lc[t + 256]) gb[t + 256] = atomicAdd(&bcur[t + 256], lc[t + 256]);
    __syncthreads();
#pragma unroll
    for (int i = 0; i < 32; ++i) {
        if (rb[i] >= 0) {
            int e = base + i * 256 + t;
            int b = rb[i] >> 13, r = rb[i] & 8191;
            ebuf[gb[b] + r] = src[e] | ((dst[e] & 255) << 20);
        }
    }
}

__global__ __launch_bounds__(256) void buildcsr(const int* __restrict__ ebuf,
                                                const int* __restrict__ bbase,
                                                const int* __restrict__ bcnt,
                                                int* __restrict__ rowptr,
                                                int* __restrict__ colarr,
                                                float* __restrict__ dinv, int N) {
    int b = blockIdx.x;
    int t = threadIdx.x;
    int start = bbase[b];
    int cnt = bcnt[b];
    __shared__ int nc[256];
    __shared__ int s[256];
    __shared__ int ncur[256];
    nc[t] = 0;
    __syncthreads();
    for (int e = t; e < cnt; e += 256) atomicAdd(&nc[ebuf[start + e] >> 20], 1);
    __syncthreads();
    int own = nc[t];
    s[t] = own;
    __syncthreads();
    for (int off = 1; off < 256; off <<= 1) {
        int add = (t >= off) ? s[t - off] : 0;
        __syncthreads();
        s[t] += add;
        __syncthreads();
    }
    int rowbase = start + s[t] - own;
    int n0 = b << 8;
    if (n0 + t < N) {
        rowptr[n0 + t] = rowbase;
        dinv[n0 + t] = rsqrtf((float)(own + 1));
    }
    ncur[t] = rowbase;
    __syncthreads();
    for (int e = t; e < cnt; e += 256) {
        int pe = ebuf[start + e];
        int slot = atomicAdd(&ncur[pe >> 20], 1);
        colarr[slot] = pe & 0xFFFFF;
    }
}

// ------- split W [K][N] fp32 -> fp16 hi/lo in MFMA FRAGMENT ORDER -------
__global__ __launch_bounds__(256) void split_wt_frag(const float* __restrict__ W,
                                                     _Float16* __restrict__ hi,
                                                     _Float16* __restrict__ lo,
                                                     int K, int N) {
    int idx = blockIdx.x * 256 + threadIdx.x;
    if (idx >= K * N) return;
    int NT = N >> 4;
    int j = idx & 7;
    int l = (idx >> 3) & 63;
    int f = idx >> 9;
    int nt = f % NT;
    int kc = f / NT;
    int k = kc * 32 + (l >> 4) * 8 + j;
    int n = nt * 16 + (l & 15);
    float v = W[k * N + n];
    _Float16 h = (_Float16)v;
    hi[idx] = h;
    lo[idx] = (_Float16)(v - (float)h);
}

// ---------------- fp16 MFMA GEMM (unchanged) ----------------
template <int BN, int KTOT, bool AFP16>
__global__ __launch_bounds__(256, 3) void gemm_f16(const void* __restrict__ Araw,
                                                   const _Float16* __restrict__ Bh_g,
                                                   const _Float16* __restrict__ Bl_g,
                                                   const float* __restrict__ dinv,
                                                   _Float16* __restrict__ C, int M) {
    constexpr int NT = BN / 16;
    constexpr int FPW = (2 * NT) / 4;
    __shared__ _Float16 Ah[128][72];
    __shared__ _Float16 Bsh[2 * NT * 512];
    __shared__ _Float16 Bsl[2 * NT * 512];

    const int tid = threadIdx.x;
    const int wave = tid >> 6;
    const int lane = tid & 63;
    const int lm = lane & 15;
    const int q = lane >> 4;
    const int m0 = blockIdx.x * 128;

    f32x4 acc[2][NT];
#pragma unroll
    for (int a = 0; a < 2; ++a)
#pragma unroll
        for (int b = 0; b < NT; ++b) acc[a][b] = (f32x4){0.f, 0.f, 0.f, 0.f};

    for (int k0 = 0; k0 < KTOT; k0 += 64) {
        const int kc0 = k0 >> 5;
        const _Float16* bh_base = Bh_g + (size_t)kc0 * NT * 512;
        const _Float16* bl_base = Bl_g + (size_t)kc0 * NT * 512;
#pragma unroll
        for (int i = 0; i < FPW; ++i) {
            int f = wave * FPW + i;
            async_copy16(&Bsh[f * 512 + lane * 8], bh_base + f * 512 + lane * 8);
            async_copy16(&Bsl[f * 512 + lane * 8], bl_base + f * 512 + lane * 8);
        }
#pragma unroll
        for (int i = 0; i < 4; ++i) {
            int flat = tid + i * 256;
            int row = flat >> 3;
            int kk = (flat & 7) << 3;
            int gr = m0 + row;
            if (AFP16) {
                uint4 hv = make_uint4(0u, 0u, 0u, 0u);
                if (gr < M)
                    hv = *(const uint4*)&((const _Float16*)Araw)[(size_t)gr * KTOT + k0 + kk];
                *(uint4*)&Ah[row][kk] = hv;
            } else {
                const float* Af = (const float*)Araw;
                float4 v0 = make_float4(0.f, 0.f, 0.f, 0.f);
                float4 v1 = make_float4(0.f, 0.f, 0.f, 0.f);
                if (gr < M) {
                    v0 = *(const float4*)&Af[(size_t)gr * KTOT + k0 + kk];
                    v1 = *(const float4*)&Af[(size_t)gr * KTOT + k0 + kk + 4];
                }
                f16x8 h;
                h[0] = (_Float16)v0.x; h[1] = (_Float16)v0.y;
                h[2] = (_Float16)v0.z; h[3] = (_Float16)v0.w;
                h[4] = (_Float16)v1.x; h[5] = (_Float16)v1.y;
                h[6] = (_Float16)v1.z; h[7] = (_Float16)v1.w;
                *(f16x8*)&Ah[row][kk] = h;
            }
        }
        __syncthreads();

#pragma unroll
        for (int dkc = 0; dkc < 2; ++dkc) {
            f16x8 a[2];
#pragma unroll
            for (int mt = 0; mt < 2; ++mt)
                a[mt] = *(const f16x8*)&Ah[wave * 32 + mt * 16 + lm][dkc * 32 + q * 8];
#pragma unroll
            for (int nt = 0; nt < NT; ++nt) {
                f16x8 bh = *(const f16x8*)&Bsh[(dkc * NT + nt) * 512 + lane * 8];
                f16x8 bl = *(const f16x8*)&Bsl[(dkc * NT + nt) * 512 + lane * 8];
#pragma unroll
                for (int mt = 0; mt < 2; ++mt) {
                    acc[mt][nt] = __builtin_amdgcn_mfma_f32_16x16x32_f16(a[mt], bh, acc[mt][nt], 0, 0, 0);
                    acc[mt][nt] = __builtin_amdgcn_mfma_f32_16x16x32_f16(a[mt], bl, acc[mt][nt], 0, 0, 0);
                }
            }
        }
        __syncthreads();
    }

#pragma unroll
    for (int mt = 0; mt < 2; ++mt) {
#pragma unroll
        for (int i = 0; i < 4; ++i) {
            int r = m0 + wave * 32 + mt * 16 + q * 4 + i;
            if (r < M) {
                float dv = dinv[r];
#pragma unroll
                for (int nt = 0; nt < NT; ++nt) {
                    C[(size_t)r * BN + nt * 16 + lm] = (_Float16)(acc[mt][nt][i] * dv);
                }
            }
        }
    }
}

// ---------------- aggregation v3: uint4 gathers, masked remainders ----------------
__device__ __forceinline__ void acc8(float* a, uint4 v) {
    float2 f0 = __half22float2(*(const __half2*)&v.x);
    float2 f1 = __half22float2(*(const __half2*)&v.y);
    float2 f2 = __half22float2(*(const __half2*)&v.z);
    float2 f3 = __half22float2(*(const __half2*)&v.w);
    a[0] += f0.x; a[1] += f0.y; a[2] += f1.x; a[3] += f1.y;
    a[4] += f2.x; a[5] += f2.y; a[6] += f3.x; a[7] += f3.y;
}

// 128 ch: wave per node; 4 groups of 16 lanes -> 4 edges per load instruction
// (1 KB/inst). 8 fp16 channels per lane. Butterfly xor16+xor32; sel==0 stores fp16.
__global__ __launch_bounds__(256) void agg128(const _Float16* __restrict__ g,
                                              const int* __restrict__ rowptr,
                                              const int* __restrict__ colarr,
                                              const float* __restrict__ dinv,
                                              const float* __restrict__ bias,
                                              _Float16* __restrict__ out, int n) {
    int node = blockIdx.x * 4 + (threadIdx.x >> 6);
    int lane = threadIdx.x & 63;
    if (node >= n) return;
    int sel = lane >> 4;        // 0..3
    int co = (lane & 15) << 3;  // 8 fp16 channels

    int beg = rowptr[node];
    int end = rowptr[node + 1];

    float a[8] = {0.f, 0.f, 0.f, 0.f, 0.f, 0.f, 0.f, 0.f};
    if (sel == 0) acc8(a, *(const uint4*)&g[(node << 7) + co]);  // self loop

    int p = beg;
    for (; p + 16 <= end; p += 16) {
        int r0 = colarr[p + sel];
        int r1 = colarr[p + 4 + sel];
        int r2 = colarr[p + 8 + sel];
        int r3 = colarr[p + 12 + sel];
        uint4 v0 = *(const uint4*)&g[(r0 << 7) + co];
        uint4 v1 = *(const uint4*)&g[(r1 << 7) + co];
        uint4 v2 = *(const uint4*)&g[(r2 << 7) + co];
        uint4 v3 = *(const uint4*)&g[(r3 << 7) + co];
        acc8(a, v0); acc8(a, v1); acc8(a, v2); acc8(a, v3);
    }
    for (; p + 4 <= end; p += 4) {
        int r = colarr[p + sel];
        acc8(a, *(const uint4*)&g[(r << 7) + co]);
    }
    int rem = end - p;
    if (sel < rem) {
        int r = colarr[p + sel];
        acc8(a, *(const uint4*)&g[(r << 7) + co]);
    }

#pragma unroll
    for (int i = 0; i < 8; ++i) {
        a[i] += __shfl(a[i], lane ^ 16);
        a[i] += __shfl(a[i], lane ^ 32);
    }

    if (sel == 0) {
        float dv = dinv[node];
        float4 b0 = *(const float4*)&bias[co];
        float4 b1 = *(const float4*)&bias[co + 4];
        float o0 = fmaxf(fmaf(a[0], dv, b0.x), 0.f);
        float o1 = fmaxf(fmaf(a[1], dv, b0.y), 0.f);
        float o2 = fmaxf(fmaf(a[2], dv, b0.z), 0.f);
        float o3 = fmaxf(fmaf(a[3], dv, b0.w), 0.f);
        float o4 = fmaxf(fmaf(a[4], dv, b1.x), 0.f);
        float o5 = fmaxf(fmaf(a[5], dv, b1.y), 0.f);
        float o6 = fmaxf(fmaf(a[6], dv, b1.z), 0.f);
        float o7 = fmaxf(fmaf(a[7], dv, b1.w), 0.f);
        __half2 h0 = __floats2half2_rn(o0, o1);
        __half2 h1 = __floats2half2_rn(o2, o3);
        __half2 h2 = __floats2half2_rn(o4, o5);
        __half2 h3 = __floats2half2_rn(o6, o7);
        uint4 pk = make_uint4(*(unsigned*)&h0, *(unsigned*)&h1,
                              *(unsigned*)&h2, *(unsigned*)&h3);
        *(uint4*)&out[(node << 7) + co] = pk;
    }
}

// 64 ch: wave per node; 8 groups of 8 lanes -> 8 edges per load instruction.
// 8 fp16 channels per lane. Butterfly xor8+xor16+xor32; sel==0 stores fp32.
__global__ __launch_bounds__(256) void agg64(const _Float16* __restrict__ g,
                                             const int* __restrict__ rowptr,
                                             const int* __restrict__ colarr,
                                             const float* __restrict__ dinv,
                                             const float* __restrict__ bias,
                                             float* __restrict__ out, int n) {
    int node = blockIdx.x * 4 + (threadIdx.x >> 6);
    int lane = threadIdx.x & 63;
    if (node >= n) return;
    int sel = lane >> 3;       // 0..7
    int co = (lane & 7) << 3;  // 8 fp16 channels

    int beg = rowptr[node];
    int end = rowptr[node + 1];

    float a[8] = {0.f, 0.f, 0.f, 0.f, 0.f, 0.f, 0.f, 0.f};
    if (sel == 0) acc8(a, *(const uint4*)&g[(node << 6) + co]);  // self loop

    int p = beg;
    for (; p + 16 <= end; p += 16) {
        int r0 = colarr[p + sel];
        int r1 = colarr[p + 8 + sel];
        uint4 v0 = *(const uint4*)&g[(r0 << 6) + co];
        uint4 v1 = *(const uint4*)&g[(r1 << 6) + co];
        acc8(a, v0); acc8(a, v1);
    }
    for (; p + 8 <= end; p += 8) {
        int r = colarr[p + sel];
        acc8(a, *(const uint4*)&g[(r << 6) + co]);
    }
    int rem = end - p;
    if (sel < rem) {
        int r = colarr[p + sel];
        acc8(a, *(const uint4*)&g[(r << 6) + co]);
    }

#pragma unroll
    for (int i = 0; i < 8; ++i) {
        a[i] += __shfl(a[i], lane ^ 8);
        a[i] += __shfl(a[i], lane ^ 16);
        a[i] += __shfl(a[i], lane ^ 32);
    }

    if (sel == 0) {
        float dv = dinv[node];
        float4 b0 = *(const float4*)&bias[co];
        float4 b1 = *(const float4*)&bias[co + 4];
        float4 oA, oB;
        oA.x = fmaxf(fmaf(a[0], dv, b0.x), 0.f);
        oA.y = fmaxf(fmaf(a[1], dv, b0.y), 0.f);
        oA.z = fmaxf(fmaf(a[2], dv, b0.z), 0.f);
        oA.w = fmaxf(fmaf(a[3], dv, b0.w), 0.f);
        oB.x = fmaxf(fmaf(a[4], dv, b1.x), 0.f);
        oB.y = fmaxf(fmaf(a[5], dv, b1.y), 0.f);
        oB.z = fmaxf(fmaf(a[6], dv, b1.z), 0.f);
        oB.w = fmaxf(fmaf(a[7], dv, b1.w), 0.f);
        *(float4*)&out[(node << 6) + co] = oA;
        *(float4*)&out[(node << 6) + co + 4] = oB;
    }
}

extern "C" void kernel_launch(void* const* d_in, const int* in_sizes, int n_in,
                              void* d_out, int out_size, void* d_ws, size_t ws_size,
                              hipStream_t stream) {
    const float* x  = (const float*)d_in[0];
    const int*   ei = (const int*)d_in[1];
    const float* W1 = (const float*)d_in[2];
    const float* b1 = (const float*)d_in[3];
    const float* W2 = (const float*)d_in[4];
    const float* b2 = (const float*)d_in[5];
    float* out = (float*)d_out;

    const int E = in_sizes[1] / 2;
    const int H1 = in_sizes[3];                 // 128
    const int K1 = in_sizes[2] / H1;            // 256
    const int N = in_sizes[0] / K1;             // 100000
    const int H2 = in_sizes[4] / H1;            // 64
    const int* src = ei;
    const int* dst = ei + E;
    const int NB = (N + 255) >> 8;

    char* ws = (char*)d_ws;
    _Float16* w1th   = (_Float16*)(ws + OFF_W1TH);
    _Float16* w1tl   = (_Float16*)(ws + OFF_W1TL);
    _Float16* w2th   = (_Float16*)(ws + OFF_W2TH);
    _Float16* w2tl   = (_Float16*)(ws + OFF_W2TL);
    int*      bcnt   = (int*)(ws + OFF_BCNT);
    int*      bbase  = (int*)(ws + OFF_BBASE);
    int*      bcur   = (int*)(ws + OFF_BCUR);
    int*      rowptr = (int*)(ws + OFF_ROWPTR);
    float*    dinv   = (float*)(ws + OFF_DINV);
    int*      colarr = (int*)(ws + OFF_COL);
    int*      ebuf   = (int*)(ws + OFF_EBUF);
    _Float16* h1g    = (_Float16*)(ws + OFF_H1G);
    _Float16* h1out  = (_Float16*)(ws + OFF_H1OUT);
    _Float16* h2g    = (_Float16*)(ws + OFF_H1G);   // reuse

    hipMemsetAsync(bcnt, 0, 512 * sizeof(int), stream);
    bincount<<<256, 256, 0, stream>>>(dst, bcnt, E);
    bscan<<<1, 512, 0, stream>>>(bcnt, bbase, bcur, rowptr, NB, N, E);
    binscatter<<<(E + CHUNK - 1) / CHUNK, 256, 0, stream>>>(src, dst, bcur, ebuf, E);
    buildcsr<<<NB, 256, 0, stream>>>(ebuf, bbase, bcnt, rowptr, colarr, dinv, N);

    split_wt_frag<<<(K1 * H1 + 255) / 256, 256, 0, stream>>>(W1, w1th, w1tl, K1, H1);
    split_wt_frag<<<(H1 * H2 + 255) / 256, 256, 0, stream>>>(W2, w2th, w2tl, H1, H2);

    // layer 1
    gemm_f16<128, 256, false><<<(N + 127) / 128, 256, 0, stream>>>(x, w1th, w1tl, dinv, h1g, N);
    agg128<<<(N + 3) / 4, 256, 0, stream>>>(h1g, rowptr, colarr, dinv, b1, h1out, N);

    // layer 2
    gemm_f16<64, 128, true><<<(N + 127) / 128, 256, 0, stream>>>(h1out, w2th, w2tl, dinv, h2g, N);
    agg64<<<(N + 3) / 4, 256, 0, stream>>>(h2g, rowptr, colarr, dinv, b2, out, N);
}